// Round 12
// baseline (154.449 us; speedup 1.0000x reference)
//
#include <hip/hip_runtime.h>
#include <hip/hip_bf16.h>

#define N_SRCN 200000
#define N_DSTN 50000
#define NEDGE 800000
#define KIN 256
#define NF 192        // H*OUT = 3*64
#define SLOPE 0.2f
#define TILES16 12500 // 16-row tiles
#define NWAVES 2048   // 256 blocks x 8 waves
#define NNT 13        // 12 feat col-tiles + 1 el/er projection tile

typedef __attribute__((ext_vector_type(8))) short bf16x8;
typedef __attribute__((ext_vector_type(4))) float f32x4;

__device__ __forceinline__ unsigned short f2bf(float f) {
    union { float f; unsigned int u; } v; v.f = f;
    unsigned int u = v.u;
    return (unsigned short)((u + 0x7FFFu + ((u >> 16) & 1u)) >> 16);  // RNE
}
__device__ __forceinline__ float bf2f(unsigned short h) {
    union { unsigned int u; float f; } v; v.u = ((unsigned int)h) << 16;
    return v.f;
}
__device__ __forceinline__ unsigned int cvt2(float lo, float hi) {
    __hip_bfloat162 h = __float22bfloat162_rn(float2{lo, hi});
    union { __hip_bfloat162 h; unsigned int u; } c; c.h = h;
    return c.u;
}
__device__ __forceinline__ void gl_lds16(const void* g, void* l) {
    __builtin_amdgcn_global_load_lds(
        (const __attribute__((address_space(1))) unsigned int*)g,
        (__attribute__((address_space(3))) unsigned int*)l, 16, 0, 0);
}

// ---------------- prep: pack W into 13-tile fragment-major Wp + row_ptr ------
// Wp[((ks*13 + nt)*64 + lane)*8 + j]:
//   nt<12 : bf16(W[nt*16 + (lane&15)][ks*32 + (lane>>4)*8 + j])
//   nt==12: projection tile — col cc=lane&15: cc<3 -> (W^T attn_l)_cc,
//           3<=cc<6 -> (W^T attn_r)_{cc-3}, else 0.
__global__ void prep_kernel(const float* __restrict__ W,
                            const float* __restrict__ attn_l, const float* __restrict__ attn_r,
                            unsigned short* __restrict__ Wp,
                            const int* __restrict__ dst, int* __restrict__ rp) {
    const int bid = blockIdx.x;
    if (bid < 26) {
        int tid = bid * 256 + threadIdx.x;
        if (tid >= NNT * 8 * 64) return;
        int lane = tid & 63;
        int g = tid >> 6;
        int nt = g % NNT, ks = g / NNT;
        int k = ks * 32 + (lane >> 4) * 8;
        unsigned short* o = &Wp[tid * 8];
        if (nt < 12) {
            int col = nt * 16 + (lane & 15);
            const float* wsrc = &W[col * KIN + k];
            #pragma unroll
            for (int j = 0; j < 8; ++j) o[j] = f2bf(wsrc[j]);
        } else {
            int cc = lane & 15;
            #pragma unroll
            for (int j = 0; j < 8; ++j) {
                float s = 0.f;
                if (cc < 6) {
                    const int h = cc < 3 ? cc : cc - 3;
                    const float* aw = cc < 3 ? attn_l : attn_r;
                    for (int f = 0; f < 64; ++f)
                        s += aw[h * 64 + f] * W[(h * 64 + f) * KIN + k + j];
                }
                o[j] = f2bf(s);
            }
        }
    } else {
        int d = (bid - 26) * 256 + threadIdx.x;
        if (d > N_DSTN) return;
        int lo = 0, hi = NEDGE;
        while (lo < hi) {
            int mid = (lo + hi) >> 1;
            if (dst[mid] < d) lo = mid + 1; else hi = mid;
        }
        rp[d] = lo;
    }
}

// ---------------- GEMM: feat = x @ W^T (bf16 MFMA), el/er as GEMM columns ----
// 256 blocks x 512 thr (1 block/CU, 104KB LDS, 8 waves/CU). Wp in LDS once;
// barrier-free independent waves; FULL-TILE register prefetch (16 float4,
// pinned by sched_barrier) consumed one tile later -> A latency fully hidden.
// launch_bounds(512,1) -> VGPR cap 512, live set ~160.
__global__ void __launch_bounds__(512, 1)
gemm_feat(const float* __restrict__ x, const unsigned short* __restrict__ Wp,
          unsigned short* __restrict__ feat,
          float* __restrict__ el4, float* __restrict__ er4) {
    __shared__ unsigned short Bl[NNT * 8 * 512];   // 104 KB
    const int t = threadIdx.x;
    const int wid = t >> 6, lane = t & 63;
    const int al = lane & 15, ah = lane >> 4;

    // ---- stage Wp -> LDS (13 sweeps x 8KB) ----
    #pragma unroll
    for (int i = 0; i < 13; ++i) {
        const int off = (i * 8 + wid) * 1024;      // byte offset, wave-uniform
        gl_lds16((const char*)Wp + off + lane * 16, (char*)Bl + off);
    }
    asm volatile("s_waitcnt vmcnt(0)" ::: "memory");
    __syncthreads();
    // ---- no barriers after this point; waves fully independent ----

    const int gw = blockIdx.x * 8 + wid;

    #define LOADA(tl)                                                          \
        {                                                                      \
            const float* xrow = &x[(size_t)((tl) * 16 + al) * KIN + ah * 8];   \
            _Pragma("unroll")                                                  \
            for (int k = 0; k < 8; ++k) {                                      \
                pf[2 * k]     = *(const float4*)&xrow[k * 32];                 \
                pf[2 * k + 1] = *(const float4*)&xrow[k * 32 + 4];             \
            }                                                                  \
        }

    float4 pf[16];
    if (gw < TILES16) LOADA(gw)

    for (int tile = gw; tile < TILES16; tile += NWAVES) {
        // convert prefetched A to bf16 fragments (waits on pf here)
        bf16x8 av[8];
        #pragma unroll
        for (int ks = 0; ks < 8; ++ks) {
            union { bf16x8 v; unsigned int u[4]; } c;
            c.u[0] = cvt2(pf[2 * ks].x,     pf[2 * ks].y);
            c.u[1] = cvt2(pf[2 * ks].z,     pf[2 * ks].w);
            c.u[2] = cvt2(pf[2 * ks + 1].x, pf[2 * ks + 1].y);
            c.u[3] = cvt2(pf[2 * ks + 1].z, pf[2 * ks + 1].w);
            av[ks] = c.v;
        }
        __builtin_amdgcn_sched_barrier(0);
        // issue NEXT tile's loads now; they fly during this tile's compute
        const int nxt = tile + NWAVES;
        if (nxt < TILES16) LOADA(nxt)
        __builtin_amdgcn_sched_barrier(0);

        f32x4 acc[NNT] = {};
        #pragma unroll
        for (int ks = 0; ks < 8; ++ks) {
            #pragma unroll
            for (int nt = 0; nt < NNT; ++nt) {
                const bf16x8 bv = *(const bf16x8*)&Bl[(ks * NNT + nt) * 512 + lane * 8];
                acc[nt] = __builtin_amdgcn_mfma_f32_16x16x32_bf16(av[ks], bv, acc[nt], 0, 0, 0);
            }
        }

        const int r0 = tile * 16;
        // feat store (C/D layout: col=nt*16+al, row=ah*4+e  [m89])
        #pragma unroll
        for (int nt = 0; nt < 12; ++nt) {
            const int col = nt * 16 + al;
            #pragma unroll
            for (int e = 0; e < 4; ++e) {
                const int row = r0 + ah * 4 + e;
                feat[(size_t)row * NF + col] = f2bf(acc[nt][e]);
            }
        }
        // el/er from projection tile (cols 0-2 = el heads, 3-5 = er heads)
        #pragma unroll
        for (int e = 0; e < 4; ++e) {
            const int row = r0 + ah * 4 + e;
            const float v = acc[12][e];
            if (al < 3) el4[(size_t)row * 4 + al] = v;
            else if (al < 6 && row < N_DSTN) er4[(size_t)row * 4 + (al - 3)] = v;
        }
    }
    #undef LOADA
}

// ---------------- gather: edge softmax (no max shift) + weighted accumulate --
__launch_bounds__(256)
__global__ void gather_kernel(const unsigned short* __restrict__ feat,
                              const float* __restrict__ el4, const float* __restrict__ er4,
                              const int* __restrict__ src, const int* __restrict__ rp,
                              float* __restrict__ out) {
    const int lane = threadIdx.x & 63;
    const int d = (blockIdx.x * blockDim.x + threadIdx.x) >> 6;
    if (d >= N_DSTN) return;
    const int lo = rp[d], hi = rp[d + 1];
    const float4 erv = *(const float4*)&er4[(size_t)d * 4];

    float a0 = 0.f, a1 = 0.f, a2 = 0.f, s0 = 0.f, s1 = 0.f, s2 = 0.f;
    for (int base = lo; base < hi; base += 64) {
        const int cnt = min(64, hi - base);
        int sv = 0; float w0 = 0.f, w1 = 0.f, w2 = 0.f;
        if (lane < cnt) {
            sv = src[base + lane];
            const float4 elv = *(const float4*)&el4[(size_t)sv * 4];
            float e0 = elv.x + erv.x; e0 = e0 >= 0.f ? e0 : SLOPE * e0; w0 = __expf(e0);
            float e1 = elv.y + erv.y; e1 = e1 >= 0.f ? e1 : SLOPE * e1; w1 = __expf(e1);
            float e2 = elv.z + erv.z; e2 = e2 >= 0.f ? e2 : SLOPE * e2; w2 = __expf(e2);
        }
        int j = 0;
        for (; j + 8 <= cnt; j += 8) {
            unsigned short f0[8], f1[8], f2[8];
            float u0[8], u1[8], u2[8];
            #pragma unroll
            for (int q = 0; q < 8; ++q) {
                const int sj = __shfl(sv, j + q);
                const unsigned short* fp = &feat[(size_t)sj * NF + lane];
                f0[q] = fp[0]; f1[q] = fp[64]; f2[q] = fp[128];
                u0[q] = __shfl(w0, j + q);
                u1[q] = __shfl(w1, j + q);
                u2[q] = __shfl(w2, j + q);
            }
            #pragma unroll
            for (int q = 0; q < 8; ++q) {
                s0 += u0[q]; a0 += u0[q] * bf2f(f0[q]);
                s1 += u1[q]; a1 += u1[q] * bf2f(f1[q]);
                s2 += u2[q]; a2 += u2[q] * bf2f(f2[q]);
            }
        }
        for (; j < cnt; ++j) {
            const int sj = __shfl(sv, j);
            const float u0 = __shfl(w0, j);
            const float u1 = __shfl(w1, j);
            const float u2 = __shfl(w2, j);
            const unsigned short* fp = &feat[(size_t)sj * NF + lane];
            s0 += u0; a0 += u0 * bf2f(fp[0]);
            s1 += u1; a1 += u1 * bf2f(fp[64]);
            s2 += u2; a2 += u2 * bf2f(fp[128]);
        }
    }
    if (hi == lo) { s0 = 1.f; s1 = 1.f; s2 = 1.f; }
    float* op = &out[(size_t)d * NF];
    op[lane]       = a0 / s0;
    op[64 + lane]  = a1 / s1;
    op[128 + lane] = a2 / s2;
}

extern "C" void kernel_launch(void* const* d_in, const int* in_sizes, int n_in,
                              void* d_out, int out_size, void* d_ws, size_t ws_size,
                              hipStream_t stream) {
    const float* x      = (const float*)d_in[0];
    const float* W      = (const float*)d_in[1];
    const float* attn_l = (const float*)d_in[2];
    const float* attn_r = (const float*)d_in[3];
    const int*   src    = (const int*)d_in[4];
    const int*   dst    = (const int*)d_in[5];
    float* out = (float*)d_out;

    char* ws = (char*)d_ws;
    unsigned short* feat = (unsigned short*)ws;             // 76,800,000 B
    float* el4 = (float*)(ws + 76800000);                   // 3,200,000 B
    float* er4 = (float*)(ws + 80000000);                   //   800,000 B
    unsigned short* Wp = (unsigned short*)(ws + 80800000);  //   106,496 B
    int*   rp = (int*)(ws + 80906496);                      //   200,004 B

    prep_kernel<<<26 + 196, 256, 0, stream>>>(W, attn_l, attn_r, Wp, dst, rp);
    gemm_feat<<<256, 512, 0, stream>>>(x, Wp, feat, el4, er4);
    gather_kernel<<<12500, 256, 0, stream>>>(feat, el4, er4, src, rp, out);
}